// Round 6
// baseline (279.061 us; speedup 1.0000x reference)
//
#include <hip/hip_runtime.h>
#include <math.h>

// Problem constants (reference: n=8192, d=4096, fp32)
#define NROWS 8192
#define NCOLS 4096
#define NCOLS4 (NCOLS / 4)
#define TEMP_INV 0.01f              // 1/TEMPERATURE

#define STRIPS 4                    // column strips of 1024 floats
#define CHUNKS 512                  // row chunks
#define CHUNK_ROWS (NROWS / CHUNKS) // 16
#define STREAM_BLKS (STRIPS * CHUNKS) // 2048 blocks, 8 per CU (full occupancy)

// ---- Kernel 1: per-chunk partial column sums (pure stores) -----------------
__global__ __launch_bounds__(256)
void colsum_partial_kernel(const float* __restrict__ g,
                           float* __restrict__ partial) {
    const int strip = blockIdx.x & (STRIPS - 1);
    const int chunk = blockIdx.x >> 2;
    const int col   = strip * 1024 + threadIdx.x * 4;
    const float* p  = g + (size_t)chunk * CHUNK_ROWS * NCOLS + col;
    float4 acc = make_float4(0.f, 0.f, 0.f, 0.f);
    #pragma unroll
    for (int r = 0; r < CHUNK_ROWS; ++r) {
        float4 v = *reinterpret_cast<const float4*>(p);
        acc.x += v.x; acc.y += v.y; acc.z += v.z; acc.w += v.w;
        p += NCOLS;
    }
    *reinterpret_cast<float4*>(partial + (size_t)chunk * NCOLS + col) = acc;
}

// ---- Kernel 2: reduce partial[CHUNKS][NCOLS] -> colsum; zero d_out ---------
// 64 blocks x 256 threads; 16 f4-cols per block, 16 chunk-groups
__global__ __launch_bounds__(256)
void reduce_kernel(const float* __restrict__ partial, float* __restrict__ dst,
                   float* __restrict__ out) {
    const int tid = threadIdx.x;
    if (blockIdx.x < 4)   // zero the output accumulator (pool atomics land later)
        reinterpret_cast<float4*>(out)[blockIdx.x * 256 + tid] =
            make_float4(0.f, 0.f, 0.f, 0.f);

    const int f4  = blockIdx.x * 16 + (tid & 15);
    const int grp = tid >> 4;
    const float4* p4 = reinterpret_cast<const float4*>(partial);
    float4 acc = make_float4(0.f, 0.f, 0.f, 0.f);
    #pragma unroll 8
    for (int c = grp; c < CHUNKS; c += 16) {
        float4 v = p4[(size_t)c * NCOLS4 + f4];
        acc.x += v.x; acc.y += v.y; acc.z += v.z; acc.w += v.w;
    }
    __shared__ float4 red[256];
    red[tid] = acc;
    __syncthreads();
    #pragma unroll
    for (int s = 128; s >= 16; s >>= 1) {
        if (tid < s) {
            float4 o = red[tid + s];
            red[tid].x += o.x; red[tid].y += o.y;
            red[tid].z += o.z; red[tid].w += o.w;
        }
        __syncthreads();
    }
    if (tid < 16)
        reinterpret_cast<float4*>(dst)[blockIdx.x * 16 + tid] = red[tid];
}

// ---- Kernel 3: scores[i] = G[i,:] . colsum (1 row per wave) ----------------
// 2048 blocks x 256 threads
__global__ __launch_bounds__(256)
void scores_kernel(const float* __restrict__ g, const float* __restrict__ colsum,
                   float* __restrict__ scores) {
    __shared__ float4 cs4[NCOLS4];
    #pragma unroll
    for (int k = 0; k < NCOLS4 / 256; ++k)
        cs4[k * 256 + threadIdx.x] =
            reinterpret_cast<const float4*>(colsum)[k * 256 + threadIdx.x];
    __syncthreads();

    const int wave = threadIdx.x >> 6;
    const int lane = threadIdx.x & 63;
    const int row  = blockIdx.x * 4 + wave;
    const float4* gp = reinterpret_cast<const float4*>(g) + (size_t)row * NCOLS4;

    float4 acc = make_float4(0.f, 0.f, 0.f, 0.f);   // 4 independent FMA chains
    #pragma unroll
    for (int k = 0; k < 16; ++k) {
        const int idx = k * 64 + lane;
        float4 v = gp[idx];
        float4 c = cs4[idx];
        acc.x += v.x * c.x; acc.y += v.y * c.y;
        acc.z += v.z * c.z; acc.w += v.w * c.w;
    }
    float s = (acc.x + acc.y) + (acc.z + acc.w);
    #pragma unroll
    for (int off = 32; off; off >>= 1) s += __shfl_xor(s, off, 64);
    if (lane == 0) scores[row] = s;
}

// ---- Kernel 4: per-block redundant softmax stats + weighted pooling --------
// 2048 blocks x 256 threads; atomicAdd into pre-zeroed d_out
__global__ __launch_bounds__(256)
void pool_kernel(const float* __restrict__ g, const float* __restrict__ scores,
                 float* __restrict__ out) {
    const int tid   = threadIdx.x;
    const int strip = blockIdx.x & (STRIPS - 1);
    const int chunk = blockIdx.x >> 2;
    const int wave  = tid >> 6;
    const int lane  = tid & 63;

    __shared__ float red[8];
    __shared__ float wsm[CHUNK_ROWS];

    // stage all 8192 scores into registers (32 per thread)
    const float4* s4 = reinterpret_cast<const float4*>(scores);
    float4 sv[8];
    float lm = -INFINITY;
    #pragma unroll
    for (int k = 0; k < 8; ++k) {
        sv[k] = s4[k * 256 + tid];
        lm = fmaxf(lm, fmaxf(fmaxf(sv[k].x, sv[k].y), fmaxf(sv[k].z, sv[k].w)));
    }
    #pragma unroll
    for (int off = 32; off; off >>= 1) lm = fmaxf(lm, __shfl_xor(lm, off, 64));
    if (lane == 0) red[wave] = lm;
    __syncthreads();
    const float m = fmaxf(fmaxf(red[0], red[1]), fmaxf(red[2], red[3]));

    float ls = 0.f;
    #pragma unroll
    for (int k = 0; k < 8; ++k) {
        ls += __expf((sv[k].x - m) * TEMP_INV)
            + __expf((sv[k].y - m) * TEMP_INV)
            + __expf((sv[k].z - m) * TEMP_INV)
            + __expf((sv[k].w - m) * TEMP_INV);
    }
    #pragma unroll
    for (int off = 32; off; off >>= 1) ls += __shfl_xor(ls, off, 64);
    if (lane == 0) red[4 + wave] = ls;
    __syncthreads();
    const float invZ = 1.0f / (red[4] + red[5] + red[6] + red[7]);

    // weights for this block's 16 rows
    if (tid < CHUNK_ROWS) {
        const float s = scores[chunk * CHUNK_ROWS + tid];
        wsm[tid] = __expf((s - m) * TEMP_INV) * invZ;
    }
    __syncthreads();

    const int col  = strip * 1024 + tid * 4;
    const float* p = g + (size_t)chunk * CHUNK_ROWS * NCOLS + col;
    float4 acc = make_float4(0.f, 0.f, 0.f, 0.f);
    #pragma unroll
    for (int r = 0; r < CHUNK_ROWS; ++r) {
        const float wt = wsm[r];            // LDS broadcast, conflict-free
        float4 v = *reinterpret_cast<const float4*>(p);
        acc.x += wt * v.x; acc.y += wt * v.y;
        acc.z += wt * v.z; acc.w += wt * v.w;
        p += NCOLS;
    }
    atomicAdd(&out[col + 0], acc.x);
    atomicAdd(&out[col + 1], acc.y);
    atomicAdd(&out[col + 2], acc.z);
    atomicAdd(&out[col + 3], acc.w);
}

extern "C" void kernel_launch(void* const* d_in, const int* in_sizes, int n_in,
                              void* d_out, int out_size, void* d_ws, size_t ws_size,
                              hipStream_t stream) {
    const float* grad = (const float*)d_in[0];
    float* out = (float*)d_out;

    // ws layout: partial [512][4096] f32 (8 MiB), colsum [4096], scores [8192]
    float* partial = (float*)d_ws;
    float* colsum  = partial + (size_t)CHUNKS * NCOLS;
    float* scores  = colsum + NCOLS;

    colsum_partial_kernel<<<STREAM_BLKS, 256, 0, stream>>>(grad, partial);
    reduce_kernel<<<64, 256, 0, stream>>>(partial, colsum, out);
    scores_kernel<<<NROWS / 4, 256, 0, stream>>>(grad, colsum, scores);
    pool_kernel<<<STREAM_BLKS, 256, 0, stream>>>(grad, scores, out);
}

// Round 7
// 236.746 us; speedup vs baseline: 1.1787x; 1.1787x over previous
//
#include <hip/hip_runtime.h>
#include <math.h>

// Problem constants (reference: n=8192, d=4096, fp32)
#define NROWS 8192
#define NCOLS 4096
#define NCOLS4 (NCOLS / 4)
#define TEMP_INV 0.01f              // 1/TEMPERATURE

// ---- colsum pass geometry (R5 config: best measured) ----
#define STRIPS 4                    // column strips of 1024 floats
#define CS_CHUNKS 256               // row chunks
#define CS_ROWS (NROWS / CS_CHUNKS) // 32 rows per chunk
#define CS_BLKS (STRIPS * CS_CHUNKS)// 1024 blocks

// ---- fused scores+pool geometry ----
#define FB 512                      // fused blocks (2/CU)
#define WPB 4                       // waves per block
#define NWAVE (FB * WPB)            // 2048 waves
#define RPW (NROWS / NWAVE)         // 4 rows per wave
#define KPL (NCOLS4 / 64)           // 16 float4 per lane

// ---- combine geometry ----
#define WGRP 16                     // w-groups
#define WPG (NWAVE / WGRP)          // 128 waves per group
#define CGRP 4                      // column groups (256 f4-cols each)

// ---- Kernel 1: per-chunk partial column sums (pure stores) -----------------
__global__ __launch_bounds__(256)
void colsum_partial_kernel(const float* __restrict__ g,
                           float* __restrict__ partial) {
    const int strip = blockIdx.x & (STRIPS - 1);
    const int chunk = blockIdx.x >> 2;
    const int col   = strip * 1024 + threadIdx.x * 4;
    const float* p  = g + (size_t)chunk * CS_ROWS * NCOLS + col;
    float4 acc = make_float4(0.f, 0.f, 0.f, 0.f);
    #pragma unroll
    for (int r = 0; r < CS_ROWS; ++r) {
        float4 v = *reinterpret_cast<const float4*>(p);
        acc.x += v.x; acc.y += v.y; acc.z += v.z; acc.w += v.w;
        p += NCOLS;
    }
    *reinterpret_cast<float4*>(partial + (size_t)chunk * NCOLS + col) = acc;
}

// ---- Kernel 2: reduce partial[CS_CHUNKS][NCOLS] -> colsum; zero d_out ------
__global__ __launch_bounds__(256)
void reduce_kernel(const float* __restrict__ partial, float* __restrict__ dst,
                   float* __restrict__ out) {
    const int tid = threadIdx.x;
    if (blockIdx.x < 4)   // zero the output accumulator (combine atomics later)
        reinterpret_cast<float4*>(out)[blockIdx.x * 256 + tid] =
            make_float4(0.f, 0.f, 0.f, 0.f);

    const int f4  = blockIdx.x * 16 + (tid & 15);
    const int grp = tid >> 4;                 // 16 chunk-groups
    const float4* p4 = reinterpret_cast<const float4*>(partial);
    float4 acc = make_float4(0.f, 0.f, 0.f, 0.f);
    #pragma unroll 4
    for (int c = grp; c < CS_CHUNKS; c += 16) {
        float4 v = p4[(size_t)c * NCOLS4 + f4];
        acc.x += v.x; acc.y += v.y; acc.z += v.z; acc.w += v.w;
    }
    __shared__ float4 red[256];
    red[tid] = acc;
    __syncthreads();
    #pragma unroll
    for (int s = 128; s >= 16; s >>= 1) {
        if (tid < s) {
            float4 o = red[tid + s];
            red[tid].x += o.x; red[tid].y += o.y;
            red[tid].z += o.z; red[tid].w += o.w;
        }
        __syncthreads();
    }
    if (tid < 16)
        reinterpret_cast<float4*>(dst)[blockIdx.x * 16 + tid] = red[tid];
}

// ---- Kernel 3: fused scores + online-softmax weighted accumulate -----------
// 512 blocks x 256 threads; wave owns 4 rows; row read ONCE (regs), used for
// both the dot product and the weighted accumulate. Flash-style local (m,Z).
__global__ __launch_bounds__(256)
void fused_kernel(const float* __restrict__ g, const float* __restrict__ colsum,
                  float* __restrict__ pnum, float2* __restrict__ mz) {
    __shared__ float4 cs4[NCOLS4];            // 16 KiB
    for (int k = threadIdx.x; k < NCOLS4; k += 256)
        cs4[k] = reinterpret_cast<const float4*>(colsum)[k];
    __syncthreads();

    const int wave = threadIdx.x >> 6;
    const int lane = threadIdx.x & 63;
    const int wid  = blockIdx.x * WPB + wave;

    float4 acc[KPL];
    #pragma unroll
    for (int k = 0; k < KPL; ++k) acc[k] = make_float4(0.f, 0.f, 0.f, 0.f);
    float m = -INFINITY, Z = 0.f;

    #pragma unroll
    for (int r = 0; r < RPW; ++r) {
        const int row = wid * RPW + r;
        const float4* rp = reinterpret_cast<const float4*>(g)
                         + (size_t)row * NCOLS4;
        float4 v[KPL];
        float4 d = make_float4(0.f, 0.f, 0.f, 0.f);
        #pragma unroll
        for (int k = 0; k < KPL; ++k) {
            v[k] = rp[k * 64 + lane];         // coalesced 1 KiB/instr
            float4 c = cs4[k * 64 + lane];
            d.x += v[k].x * c.x; d.y += v[k].y * c.y;
            d.z += v[k].z * c.z; d.w += v[k].w * c.w;
        }
        float s = (d.x + d.y) + (d.z + d.w);
        #pragma unroll
        for (int off = 32; off; off >>= 1) s += __shfl_xor(s, off, 64);

        // online softmax accumulate (wave-uniform, branch-free)
        const float mnew  = fmaxf(m, s);
        const float scale = (m == -INFINITY) ? 0.f
                          : __expf((m - mnew) * TEMP_INV);
        const float e     = __expf((s - mnew) * TEMP_INV);
        Z = Z * scale + e;
        #pragma unroll
        for (int k = 0; k < KPL; ++k) {
            acc[k].x = acc[k].x * scale + e * v[k].x;
            acc[k].y = acc[k].y * scale + e * v[k].y;
            acc[k].z = acc[k].z * scale + e * v[k].z;
            acc[k].w = acc[k].w * scale + e * v[k].w;
        }
        m = mnew;
    }

    float4* pp = reinterpret_cast<float4*>(pnum) + (size_t)wid * NCOLS4;
    #pragma unroll
    for (int k = 0; k < KPL; ++k) pp[k * 64 + lane] = acc[k];
    if (lane == 0) mz[wid] = make_float2(m, Z);
}

// ---- Kernel 4: combine — redundant global (M,Z), rescale, atomic add -------
// 64 blocks x 256 threads: 16 w-groups x 4 col-groups
__global__ __launch_bounds__(256)
void combine_kernel(const float* __restrict__ pnum, const float2* __restrict__ mz,
                    float* __restrict__ out) {
    __shared__ float red[8];
    __shared__ float fsh[WPG];
    const int tid = threadIdx.x;
    const int wg  = blockIdx.x >> 2;
    const int cg  = blockIdx.x & 3;
    const int wave = tid >> 6, lane = tid & 63;

    // redundant global max over 2048 wave-maxima
    float lm = -INFINITY;
    for (int i = tid; i < NWAVE; i += 256) lm = fmaxf(lm, mz[i].x);
    #pragma unroll
    for (int off = 32; off; off >>= 1) lm = fmaxf(lm, __shfl_xor(lm, off, 64));
    if (lane == 0) red[wave] = lm;
    __syncthreads();
    const float M = fmaxf(fmaxf(red[0], red[1]), fmaxf(red[2], red[3]));

    // redundant global Z
    float lz = 0.f;
    for (int i = tid; i < NWAVE; i += 256)
        lz += mz[i].y * __expf((mz[i].x - M) * TEMP_INV);
    #pragma unroll
    for (int off = 32; off; off >>= 1) lz += __shfl_xor(lz, off, 64);
    if (lane == 0) red[4 + wave] = lz;
    __syncthreads();
    const float invZ = 1.0f / (red[4] + red[5] + red[6] + red[7]);

    // per-wave rescale factors for this block's w-group
    if (tid < WPG) {
        const int w = wg * WPG + tid;
        fsh[tid] = __expf((mz[w].x - M) * TEMP_INV) * invZ;
    }
    __syncthreads();

    const int col4 = cg * 256 + tid;
    float4 a = make_float4(0.f, 0.f, 0.f, 0.f);
    const float4* p4 = reinterpret_cast<const float4*>(pnum);
    #pragma unroll 4
    for (int w = 0; w < WPG; ++w) {
        float4 v = p4[(size_t)(wg * WPG + w) * NCOLS4 + col4];
        const float f = fsh[w];
        a.x += f * v.x; a.y += f * v.y; a.z += f * v.z; a.w += f * v.w;
    }
    atomicAdd(&out[col4 * 4 + 0], a.x);
    atomicAdd(&out[col4 * 4 + 1], a.y);
    atomicAdd(&out[col4 * 4 + 2], a.z);
    atomicAdd(&out[col4 * 4 + 3], a.w);
}

extern "C" void kernel_launch(void* const* d_in, const int* in_sizes, int n_in,
                              void* d_out, int out_size, void* d_ws, size_t ws_size,
                              hipStream_t stream) {
    const float* grad = (const float*)d_in[0];
    float* out = (float*)d_out;

    // ws layout: pcs [256][4096] (4 MiB) | colsum [4096] |
    //            pnum [2048][4096] (32 MiB) | mz [2048] float2
    float* pcs    = (float*)d_ws;
    float* colsum = pcs + (size_t)CS_CHUNKS * NCOLS;
    float* pnum   = colsum + NCOLS;
    float2* mz    = (float2*)(pnum + (size_t)NWAVE * NCOLS);

    colsum_partial_kernel<<<CS_BLKS, 256, 0, stream>>>(grad, pcs);
    reduce_kernel<<<64, 256, 0, stream>>>(pcs, colsum, out);
    fused_kernel<<<FB, 256, 0, stream>>>(grad, colsum, pnum, mz);
    combine_kernel<<<64, 256, 0, stream>>>(pnum, mz, out);
}